// Round 3
// baseline (62.293 us; speedup 1.0000x reference)
//
#include <hip/hip_runtime.h>
#include <math.h>

// ---------------------------------------------------------------------------
// DirectVoxGO Raw2Alpha + Alphas2Weights (forward), fused per-ray scan.
//
// outputs (concatenated in d_out, float32):
//   weights[n_pts]         = alpha * T   (T = exclusive cumprod of (1-alpha))
//   alphainv_last[n_rays]  = prod over ray of (1-alpha)
//
// log(1-alpha) = -interval * softplus(density + shift); all scans in log space.
// ---------------------------------------------------------------------------

__device__ __forceinline__ float softplus_f(float x) {
    // numerically stable: max(x,0) + log1p(exp(-|x|))
    return fmaxf(x, 0.0f) + log1pf(expf(-fabsf(x)));
}

// Kernel 1: start[r] = first index i with ray_id[i] >= r, for r in [0, n_rays].
// ray_id is sorted ascending; empty rays get start[r] == start[r+1].
__global__ void seg_starts_kernel(const int* __restrict__ ray_id,
                                  int n_pts, int n_rays,
                                  int* __restrict__ start) {
    int i = blockIdx.x * blockDim.x + threadIdx.x;
    if (i >= n_pts) return;
    int cur  = ray_id[i];
    int prev = (i == 0) ? -1 : ray_id[i - 1];
    // this thread owns rays (prev, cur]
    for (int q = prev + 1; q <= cur; ++q) start[q] = i;
    if (i == n_pts - 1) {
        for (int q = cur + 1; q <= n_rays; ++q) start[q] = n_pts;
    }
}

// Kernel 2: one 64-lane wave per ray. Chunked wave-level inclusive scan of
// log(1-alpha) with a scalar carry between chunks.
__global__ void alpha_weights_kernel(const float* __restrict__ density,
                                     const float* __restrict__ shift_p,
                                     const float* __restrict__ interval_p,
                                     const int* __restrict__ start,
                                     float* __restrict__ weights,
                                     float* __restrict__ alphainv_last,
                                     int n_rays) {
    const int lane = threadIdx.x & 63;
    const int wid  = threadIdx.x >> 6;                    // wave within block
    const int r    = blockIdx.x * (blockDim.x >> 6) + wid; // one ray per wave
    if (r >= n_rays) return;

    const float shift    = shift_p[0];
    const float interval = interval_p[0];

    const int s = start[r];
    const int e = start[r + 1];

    float carry = 0.0f;  // running sum of log(1-alpha) over the ray so far
    for (int base = s; base < e; base += 64) {
        const int  idx   = base + lane;
        const bool valid = (idx < e);

        float l = 0.0f;  // log(1 - alpha); invalid lanes contribute 0 to scan
        if (valid) {
            float d = density[idx];
            l = -interval * softplus_f(d + shift);
        }

        // wave64 inclusive scan of l
        float incl = l;
        #pragma unroll
        for (int off = 1; off < 64; off <<= 1) {
            float t = __shfl_up(incl, off, 64);
            if (lane >= off) incl += t;
        }

        const float logT = carry + (incl - l);  // exclusive prefix (log T)
        if (valid) {
            const float alpha = -expm1f(l);     // 1 - exp(l), stable for small l
            weights[idx] = alpha * expf(logT);
        }

        carry += __shfl(incl, 63, 64);          // chunk total (zeros padded)
    }

    if (lane == 0) alphainv_last[r] = expf(carry);
}

extern "C" void kernel_launch(void* const* d_in, const int* in_sizes, int n_in,
                              void* d_out, int out_size, void* d_ws, size_t ws_size,
                              hipStream_t stream) {
    const float* density  = (const float*)d_in[0];
    const float* shift    = (const float*)d_in[1];   // 1-element array
    const float* interval = (const float*)d_in[2];   // 1-element array
    const int*   ray_id   = (const int*)d_in[3];
    // d_in[4] = n_rays (device scalar); derive on host from sizes instead:
    const int n_pts  = in_sizes[0];
    const int n_rays = out_size - n_pts;

    int*   start    = (int*)d_ws;                 // (n_rays + 1) ints of scratch
    float* weights  = (float*)d_out;              // [n_pts]
    float* alphainv = (float*)d_out + n_pts;      // [n_rays]

    {
        const int block = 256;
        const int grid  = (n_pts + block - 1) / block;
        seg_starts_kernel<<<grid, block, 0, stream>>>(ray_id, n_pts, n_rays, start);
    }
    {
        const int waves_per_block = 4;            // block = 256 threads
        const int block = waves_per_block * 64;
        const int grid  = (n_rays + waves_per_block - 1) / waves_per_block;
        alpha_weights_kernel<<<grid, block, 0, stream>>>(
            density, shift, interval, start, weights, alphainv, n_rays);
    }
}

// Round 4
// 32.298 us; speedup vs baseline: 1.9287x; 1.9287x over previous
//
#include <hip/hip_runtime.h>
#include <math.h>

// ---------------------------------------------------------------------------
// DirectVoxGO Raw2Alpha + Alphas2Weights (forward), fused per-ray scan.
//
// outputs (concatenated in d_out, float32):
//   weights[n_pts]         = alpha * T   (T = exclusive cumprod of (1-alpha))
//   alphainv_last[n_rays]  = prod over ray of (1-alpha)
//
// All math in log2 space with native v_exp_f32 / v_log_f32:
//   l2 = log2(1-alpha) = -interval * (max(y,0) + log2(1 + 2^-|y|)),
//        y = (density+shift) * log2(e)
//   weight_j = exp2(logT2_j) - exp2(logT2_j + l2_j)   (consecutive exp2 shared)
// ---------------------------------------------------------------------------

#define LOG2E 1.4426950408889634f

__device__ __forceinline__ float exp2_fast(float x) { return __builtin_amdgcn_exp2f(x); }
__device__ __forceinline__ float log2_fast(float x) { return __builtin_amdgcn_logf(x); }

__device__ __forceinline__ float l2_of(float d, float sh2, float negc) {
    const float y = fmaf(d, LOG2E, sh2);            // (d+shift)*log2e
    const float t = exp2_fast(-fabsf(y));           // 2^-|y|  (modifiers free)
    const float g = log2_fast(1.0f + t);            // log2(1 + 2^-|y|)
    return negc * (fmaxf(y, 0.0f) + g);             // -interval * softplus*log2e
}

// Kernel 1: start[r] = first index i with ray_id[i] >= r, r in [0, n_rays].
// ray_id sorted ascending; empty rays get start[r] == start[r+1].
__global__ void seg_starts_kernel(const int* __restrict__ ray_id,
                                  int n_pts, int n_rays,
                                  int* __restrict__ start) {
    const int i = (blockIdx.x * blockDim.x + threadIdx.x) * 4;
    if (i >= n_pts) return;
    int prev = (i == 0) ? -1 : ray_id[i - 1];
    if (i + 4 <= n_pts) {
        const int4 v = *reinterpret_cast<const int4*>(ray_id + i);
        for (int q = prev + 1; q <= v.x; ++q) start[q] = i;
        for (int q = v.x + 1;  q <= v.y; ++q) start[q] = i + 1;
        for (int q = v.y + 1;  q <= v.z; ++q) start[q] = i + 2;
        for (int q = v.z + 1;  q <= v.w; ++q) start[q] = i + 3;
        prev = v.w;
    } else {
        for (int j = 0; j < 4 && i + j < n_pts; ++j) {
            const int c = ray_id[i + j];
            for (int q = prev + 1; q <= c; ++q) start[q] = i + j;
            prev = c;
        }
    }
    if (i + 4 >= n_pts) {
        for (int q = prev + 1; q <= n_rays; ++q) start[q] = n_pts;
    }
}

// Kernel 2: one wave64 per ray, 4 consecutive elements per lane (chunk=256).
// Per-lane serial prefix + one wave scan per chunk; weights via shared exp2s.
__global__ void alpha_weights_kernel(const float* __restrict__ density,
                                     const float* __restrict__ shift_p,
                                     const float* __restrict__ interval_p,
                                     const int* __restrict__ start,
                                     float* __restrict__ weights,
                                     float* __restrict__ alphainv_last,
                                     int n_rays) {
    const int lane = threadIdx.x & 63;
    const int wid  = threadIdx.x >> 6;
    const int r    = blockIdx.x * (blockDim.x >> 6) + wid;
    if (r >= n_rays) return;

    const float shift    = shift_p[0];
    const float interval = interval_p[0];
    const float sh2  = shift * LOG2E;
    const float negc = -interval;

    const int s = start[r];
    const int e = start[r + 1];

    float carry = 0.0f;                       // running log2-transmittance
    for (int base = (s & ~3); base < e; base += 256) {
        const int  idx       = base + lane * 4;      // 16B-aligned
        const bool lane_live = (idx < e);            // idx+3 >= s always holds

        float l0 = 0.f, l1 = 0.f, l2 = 0.f, l3 = 0.f;
        unsigned rel0 = 0, len = 0;
        if (lane_live) {
            const float4 d4 = *reinterpret_cast<const float4*>(density + idx);
            rel0 = (unsigned)(idx - s);               // wraps huge if idx < s
            len  = (unsigned)(e - s);
            l0 = (rel0     < len) ? l2_of(d4.x, sh2, negc) : 0.f;
            l1 = (rel0 + 1 < len) ? l2_of(d4.y, sh2, negc) : 0.f;
            l2 = (rel0 + 2 < len) ? l2_of(d4.z, sh2, negc) : 0.f;
            l3 = (rel0 + 3 < len) ? l2_of(d4.w, sh2, negc) : 0.f;
        }

        // in-lane inclusive prefix
        const float p0 = l0;
        const float p1 = p0 + l1;
        const float p2 = p1 + l2;
        const float p3 = p2 + l3;

        // wave64 inclusive scan of lane totals
        float S = p3;
        #pragma unroll
        for (int off = 1; off < 64; off <<= 1) {
            const float t = __shfl_up(S, off, 64);
            if (lane >= off) S += t;
        }

        const float ex = carry + (S - p3);    // exclusive log2 prefix for lane
        if (lane_live) {
            const float E0 = exp2_fast(ex);
            const float E1 = exp2_fast(ex + p0);
            const float E2 = exp2_fast(ex + p1);
            const float E3 = exp2_fast(ex + p2);
            const float E4 = exp2_fast(ex + p3);
            if (idx >= s && idx + 4 <= e) {   // fully-valid fast path
                float4 w;
                w.x = E0 - E1; w.y = E1 - E2; w.z = E2 - E3; w.w = E3 - E4;
                *reinterpret_cast<float4*>(weights + idx) = w;
            } else {
                if (rel0     < len) weights[idx]     = E0 - E1;
                if (rel0 + 1 < len) weights[idx + 1] = E1 - E2;
                if (rel0 + 2 < len) weights[idx + 2] = E2 - E3;
                if (rel0 + 3 < len) weights[idx + 3] = E3 - E4;
            }
        }

        carry += __shfl(S, 63, 64);           // chunk total (padding adds 0)
    }

    if (lane == 0) alphainv_last[r] = exp2_fast(carry);
}

extern "C" void kernel_launch(void* const* d_in, const int* in_sizes, int n_in,
                              void* d_out, int out_size, void* d_ws, size_t ws_size,
                              hipStream_t stream) {
    const float* density  = (const float*)d_in[0];
    const float* shift    = (const float*)d_in[1];   // 1-element array
    const float* interval = (const float*)d_in[2];   // 1-element array
    const int*   ray_id   = (const int*)d_in[3];
    const int n_pts  = in_sizes[0];
    const int n_rays = out_size - n_pts;

    int*   start    = (int*)d_ws;                 // (n_rays + 1) ints of scratch
    float* weights  = (float*)d_out;              // [n_pts]
    float* alphainv = (float*)d_out + n_pts;      // [n_rays]

    {
        const int block = 256;
        const int work  = (n_pts + 3) / 4;
        const int grid  = (work + block - 1) / block;
        seg_starts_kernel<<<grid, block, 0, stream>>>(ray_id, n_pts, n_rays, start);
    }
    {
        const int waves_per_block = 4;            // block = 256 threads
        const int block = waves_per_block * 64;
        const int grid  = (n_rays + waves_per_block - 1) / waves_per_block;
        alpha_weights_kernel<<<grid, block, 0, stream>>>(
            density, shift, interval, start, weights, alphainv, n_rays);
    }
}

// Round 5
// 31.883 us; speedup vs baseline: 1.9538x; 1.0130x over previous
//
#include <hip/hip_runtime.h>
#include <math.h>

// ---------------------------------------------------------------------------
// DirectVoxGO Raw2Alpha + Alphas2Weights (forward), fused per-ray scan.
//
// outputs (concatenated in d_out, float32):
//   weights[n_pts]         = alpha_j * T_j,  T_j = prod_{k<j} (1-alpha_k)
//   alphainv_last[n_rays]  = prod over ray of (1-alpha)
//
// Direct multiplicative cumprod scan (no log-space):
//   fast path (interval == 0.5):  (1-alpha) = rsqrt(1 + exp2(y)),
//       y = (density+shift)*log2e          [2 trans / element, no epilogue exp]
//   general path: (1-alpha) = exp2(-c * (max(y,0) + log2(1 + 2^-|y|)))
//   weights via adjacent products: w_j = P*q_{j-1} - P*q_j  (pure FMA/sub)
// ---------------------------------------------------------------------------

#define LOG2E 1.4426950408889634f

__device__ __forceinline__ float exp2f_(float x) { return __builtin_amdgcn_exp2f(x); }
__device__ __forceinline__ float log2f_(float x) { return __builtin_amdgcn_logf(x); }
__device__ __forceinline__ float rsqf_(float x)  { return __builtin_amdgcn_rsqf(x); }

// Kernel 1: start[r] = first index i with ray_id[i] >= r, r in [0, n_rays].
// ray_id sorted ascending; empty rays get start[r] == start[r+1].
__global__ void seg_starts_kernel(const int* __restrict__ ray_id,
                                  int n_pts, int n_rays,
                                  int* __restrict__ start) {
    const int i = (blockIdx.x * blockDim.x + threadIdx.x) * 4;
    if (i >= n_pts) return;
    int prev = (i == 0) ? -1 : ray_id[i - 1];
    if (i + 4 <= n_pts) {
        const int4 v = *reinterpret_cast<const int4*>(ray_id + i);
        for (int q = prev + 1; q <= v.x; ++q) start[q] = i;
        for (int q = v.x + 1;  q <= v.y; ++q) start[q] = i + 1;
        for (int q = v.y + 1;  q <= v.z; ++q) start[q] = i + 2;
        for (int q = v.z + 1;  q <= v.w; ++q) start[q] = i + 3;
        prev = v.w;
    } else {
        for (int j = 0; j < 4 && i + j < n_pts; ++j) {
            const int c = ray_id[i + j];
            for (int q = prev + 1; q <= c; ++q) start[q] = i + j;
            prev = c;
        }
    }
    if (i + 4 >= n_pts) {
        for (int q = prev + 1; q <= n_rays; ++q) start[q] = n_pts;
    }
}

// Kernel 2: one wave64 per ray, 4 consecutive elements per lane (chunk=256).
// Multiplicative wave scan of (1-alpha); weights from adjacent partials.
__global__ void alpha_weights_kernel(const float* __restrict__ density,
                                     const float* __restrict__ shift_p,
                                     const float* __restrict__ interval_p,
                                     const int* __restrict__ start,
                                     float* __restrict__ weights,
                                     float* __restrict__ alphainv_last,
                                     int n_rays) {
    const int lane = threadIdx.x & 63;
    const int wid  = threadIdx.x >> 6;
    const int r    = blockIdx.x * (blockDim.x >> 6) + wid;
    if (r >= n_rays) return;

    const float shift = shift_p[0];
    const float c     = interval_p[0];
    const float sh2   = shift * LOG2E;
    const float negc  = -c;
    const bool  fast  = (c == 0.5f);   // wave-uniform

    const int s = start[r];
    const int e = start[r + 1];

    float carry = 1.0f;                       // running transmittance
    for (int base = (s & ~3); base < e; base += 256) {
        const int  idx       = base + lane * 4;   // 16B-aligned
        const bool lane_live = (idx < e);

        float a0 = 1.f, a1 = 1.f, a2 = 1.f, a3 = 1.f;   // (1-alpha), identity=1
        unsigned rel0 = 0, len = 0;
        if (lane_live) {
            const float4 d4 = *reinterpret_cast<const float4*>(density + idx);
            rel0 = (unsigned)(idx - s);               // wraps huge if idx < s
            len  = (unsigned)(e - s);
            const float y0 = fmaf(d4.x, LOG2E, sh2);
            const float y1 = fmaf(d4.y, LOG2E, sh2);
            const float y2 = fmaf(d4.z, LOG2E, sh2);
            const float y3 = fmaf(d4.w, LOG2E, sh2);
            if (fast) {
                a0 = (rel0     < len) ? rsqf_(1.0f + exp2f_(y0)) : 1.0f;
                a1 = (rel0 + 1 < len) ? rsqf_(1.0f + exp2f_(y1)) : 1.0f;
                a2 = (rel0 + 2 < len) ? rsqf_(1.0f + exp2f_(y2)) : 1.0f;
                a3 = (rel0 + 3 < len) ? rsqf_(1.0f + exp2f_(y3)) : 1.0f;
            } else {
                const float s0 = fmaxf(y0, 0.f) + log2f_(1.f + exp2f_(-fabsf(y0)));
                const float s1 = fmaxf(y1, 0.f) + log2f_(1.f + exp2f_(-fabsf(y1)));
                const float s2 = fmaxf(y2, 0.f) + log2f_(1.f + exp2f_(-fabsf(y2)));
                const float s3 = fmaxf(y3, 0.f) + log2f_(1.f + exp2f_(-fabsf(y3)));
                a0 = (rel0     < len) ? exp2f_(negc * s0) : 1.0f;
                a1 = (rel0 + 1 < len) ? exp2f_(negc * s1) : 1.0f;
                a2 = (rel0 + 2 < len) ? exp2f_(negc * s2) : 1.0f;
                a3 = (rel0 + 3 < len) ? exp2f_(negc * s3) : 1.0f;
            }
        }

        // in-lane inclusive prefix products
        const float q0 = a0;
        const float q1 = q0 * a1;
        const float q2 = q1 * a2;
        const float q3 = q2 * a3;

        // wave64 inclusive multiplicative scan of lane totals
        float I = q3;
        #pragma unroll
        for (int off = 1; off < 64; off <<= 1) {
            const float t = __shfl_up(I, off, 64);
            if (lane >= off) I *= t;
        }

        // exclusive product for this lane
        float Ex = __shfl_up(I, 1, 64);
        if (lane == 0) Ex = 1.0f;
        const float P = carry * Ex;           // transmittance at lane elem 0

        if (lane_live) {
            const float t0 = P * q0;
            const float t1 = P * q1;
            const float t2 = P * q2;
            const float t3 = P * q3;
            if (idx >= s && idx + 4 <= e) {   // fully-valid fast path
                float4 w;
                w.x = P - t0; w.y = t0 - t1; w.z = t1 - t2; w.w = t2 - t3;
                *reinterpret_cast<float4*>(weights + idx) = w;
            } else {
                if (rel0     < len) weights[idx]     = P  - t0;
                if (rel0 + 1 < len) weights[idx + 1] = t0 - t1;
                if (rel0 + 2 < len) weights[idx + 2] = t1 - t2;
                if (rel0 + 3 < len) weights[idx + 3] = t2 - t3;
            }
        }

        carry *= __shfl(I, 63, 64);           // chunk total (padding is 1.0)
    }

    if (lane == 0) alphainv_last[r] = carry;
}

extern "C" void kernel_launch(void* const* d_in, const int* in_sizes, int n_in,
                              void* d_out, int out_size, void* d_ws, size_t ws_size,
                              hipStream_t stream) {
    const float* density  = (const float*)d_in[0];
    const float* shift    = (const float*)d_in[1];   // 1-element array
    const float* interval = (const float*)d_in[2];   // 1-element array
    const int*   ray_id   = (const int*)d_in[3];
    const int n_pts  = in_sizes[0];
    const int n_rays = out_size - n_pts;

    int*   start    = (int*)d_ws;                 // (n_rays + 1) ints of scratch
    float* weights  = (float*)d_out;              // [n_pts]
    float* alphainv = (float*)d_out + n_pts;      // [n_rays]

    {
        const int block = 256;
        const int work  = (n_pts + 3) / 4;
        const int grid  = (work + block - 1) / block;
        seg_starts_kernel<<<grid, block, 0, stream>>>(ray_id, n_pts, n_rays, start);
    }
    {
        const int waves_per_block = 4;            // block = 256 threads
        const int block = waves_per_block * 64;
        const int grid  = (n_rays + waves_per_block - 1) / waves_per_block;
        alpha_weights_kernel<<<grid, block, 0, stream>>>(
            density, shift, interval, start, weights, alphainv, n_rays);
    }
}

// Round 6
// 30.071 us; speedup vs baseline: 2.0715x; 1.0602x over previous
//
#include <hip/hip_runtime.h>
#include <math.h>

// ---------------------------------------------------------------------------
// DirectVoxGO Raw2Alpha + Alphas2Weights (forward), fused per-ray scan.
//
// outputs (concatenated in d_out, float32):
//   weights[n_pts]         = alpha_j * T_j,  T_j = prod_{k<j} (1-alpha_k)
//   alphainv_last[n_rays]  = prod over ray of (1-alpha)
//
// Multiplicative cumprod scan via DPP (VALU-only, no LDS pipe):
//   fast path (interval == 0.5):  (1-alpha) = rsqrt(1 + exp2(y)),
//       y = (density+shift)*log2e
//   general path: (1-alpha) = exp2(-c * (max(y,0) + log2(1 + 2^-|y|)))
//   weights via adjacent products: w_j = P*q_{j-1} - P*q_j
// ---------------------------------------------------------------------------

#define LOG2E 1.4426950408889634f

__device__ __forceinline__ float exp2f_(float x) { return __builtin_amdgcn_exp2f(x); }
__device__ __forceinline__ float log2f_(float x) { return __builtin_amdgcn_logf(x); }
__device__ __forceinline__ float rsqf_(float x)  { return __builtin_amdgcn_rsqf(x); }

typedef float vf4 __attribute__((ext_vector_type(4)));

// One DPP step of a multiplicative Hillis-Steele scan: I *= dpp_move(I),
// with identity 1.0f for lanes whose source is invalid / masked rows.
// ctrl: 0x111/0x112/0x114/0x118 = row_shr:1/2/4/8, 0x142 = row_bcast:15,
// 0x143 = row_bcast:31. row_mask gates which 16-lane rows are updated.
#define MUL_DPP(I, CTRL, ROWMASK)                                             \
    do {                                                                      \
        int _t = __builtin_amdgcn_update_dpp(                                 \
            0x3f800000 /*1.0f*/, __builtin_bit_cast(int, (I)),                \
            (CTRL), (ROWMASK), 0xF, false);                                   \
        (I) *= __builtin_bit_cast(float, _t);                                 \
    } while (0)

// Kernel 1: start[r] = first index i with ray_id[i] >= r, r in [0, n_rays].
// ray_id sorted ascending; empty rays get start[r] == start[r+1].
__global__ void seg_starts_kernel(const int* __restrict__ ray_id,
                                  int n_pts, int n_rays,
                                  int* __restrict__ start) {
    const int i = (blockIdx.x * blockDim.x + threadIdx.x) * 4;
    if (i >= n_pts) return;
    int prev = (i == 0) ? -1 : ray_id[i - 1];
    if (i + 4 <= n_pts) {
        const int4 v = *reinterpret_cast<const int4*>(ray_id + i);
        for (int q = prev + 1; q <= v.x; ++q) start[q] = i;
        for (int q = v.x + 1;  q <= v.y; ++q) start[q] = i + 1;
        for (int q = v.y + 1;  q <= v.z; ++q) start[q] = i + 2;
        for (int q = v.z + 1;  q <= v.w; ++q) start[q] = i + 3;
        prev = v.w;
    } else {
        for (int j = 0; j < 4 && i + j < n_pts; ++j) {
            const int c = ray_id[i + j];
            for (int q = prev + 1; q <= c; ++q) start[q] = i + j;
            prev = c;
        }
    }
    if (i + 4 >= n_pts) {
        for (int q = prev + 1; q <= n_rays; ++q) start[q] = n_pts;
    }
}

// Kernel 2: one wave64 per ray, 4 consecutive elements per lane (chunk=256).
// DPP multiplicative wave scan of (1-alpha); weights from adjacent partials.
__global__ void alpha_weights_kernel(const float* __restrict__ density,
                                     const float* __restrict__ shift_p,
                                     const float* __restrict__ interval_p,
                                     const int* __restrict__ start,
                                     float* __restrict__ weights,
                                     float* __restrict__ alphainv_last,
                                     int n_rays) {
    const int lane = threadIdx.x & 63;
    const int wid  = threadIdx.x >> 6;
    const int r    = blockIdx.x * (blockDim.x >> 6) + wid;
    if (r >= n_rays) return;

    const float shift = shift_p[0];
    const float c     = interval_p[0];
    const float sh2   = shift * LOG2E;
    const float negc  = -c;
    const bool  fast  = (c == 0.5f);   // wave-uniform

    const int s = start[r];
    const int e = start[r + 1];

    float carry = 1.0f;                       // running transmittance
    for (int base = (s & ~3); base < e; base += 256) {
        const int  idx       = base + lane * 4;   // 16B-aligned
        const bool lane_live = (idx < e);

        float a0 = 1.f, a1 = 1.f, a2 = 1.f, a3 = 1.f;   // (1-alpha), identity=1
        unsigned rel0 = 0, len = 0;
        if (lane_live) {
            const float4 d4 = *reinterpret_cast<const float4*>(density + idx);
            rel0 = (unsigned)(idx - s);               // wraps huge if idx < s
            len  = (unsigned)(e - s);
            const float y0 = fmaf(d4.x, LOG2E, sh2);
            const float y1 = fmaf(d4.y, LOG2E, sh2);
            const float y2 = fmaf(d4.z, LOG2E, sh2);
            const float y3 = fmaf(d4.w, LOG2E, sh2);
            if (fast) {
                a0 = (rel0     < len) ? rsqf_(1.0f + exp2f_(y0)) : 1.0f;
                a1 = (rel0 + 1 < len) ? rsqf_(1.0f + exp2f_(y1)) : 1.0f;
                a2 = (rel0 + 2 < len) ? rsqf_(1.0f + exp2f_(y2)) : 1.0f;
                a3 = (rel0 + 3 < len) ? rsqf_(1.0f + exp2f_(y3)) : 1.0f;
            } else {
                const float s0 = fmaxf(y0, 0.f) + log2f_(1.f + exp2f_(-fabsf(y0)));
                const float s1 = fmaxf(y1, 0.f) + log2f_(1.f + exp2f_(-fabsf(y1)));
                const float s2 = fmaxf(y2, 0.f) + log2f_(1.f + exp2f_(-fabsf(y2)));
                const float s3 = fmaxf(y3, 0.f) + log2f_(1.f + exp2f_(-fabsf(y3)));
                a0 = (rel0     < len) ? exp2f_(negc * s0) : 1.0f;
                a1 = (rel0 + 1 < len) ? exp2f_(negc * s1) : 1.0f;
                a2 = (rel0 + 2 < len) ? exp2f_(negc * s2) : 1.0f;
                a3 = (rel0 + 3 < len) ? exp2f_(negc * s3) : 1.0f;
            }
        }

        // in-lane inclusive prefix products
        const float q0 = a0;
        const float q1 = q0 * a1;
        const float q2 = q1 * a2;
        const float q3 = q2 * a3;

        // wave64 inclusive multiplicative scan of lane totals — DPP, VALU-only
        float I = q3;
        MUL_DPP(I, 0x111, 0xF);   // row_shr:1
        MUL_DPP(I, 0x112, 0xF);   // row_shr:2
        MUL_DPP(I, 0x114, 0xF);   // row_shr:4
        MUL_DPP(I, 0x118, 0xF);   // row_shr:8   -> scan within each 16-lane row
        MUL_DPP(I, 0x142, 0xA);   // row_bcast:15 into rows 1,3
        MUL_DPP(I, 0x143, 0xC);   // row_bcast:31 into rows 2,3

        // exclusive product for this lane (single LDS op per chunk)
        float Ex = __shfl_up(I, 1, 64);
        if (lane == 0) Ex = 1.0f;
        const float P = carry * Ex;           // transmittance at lane elem 0

        if (lane_live) {
            const float t0 = P * q0;
            const float t1 = P * q1;
            const float t2 = P * q2;
            const float t3 = P * q3;
            if (idx >= s && idx + 4 <= e) {   // fully-valid fast path
                vf4 w = { P - t0, t0 - t1, t1 - t2, t2 - t3 };
                __builtin_nontemporal_store(w, reinterpret_cast<vf4*>(weights + idx));
            } else {
                if (rel0     < len) weights[idx]     = P  - t0;
                if (rel0 + 1 < len) weights[idx + 1] = t0 - t1;
                if (rel0 + 2 < len) weights[idx + 2] = t1 - t2;
                if (rel0 + 3 < len) weights[idx + 3] = t2 - t3;
            }
        }

        // chunk total via readlane (SGPR broadcast, no LDS)
        carry *= __builtin_bit_cast(
            float, __builtin_amdgcn_readlane(__builtin_bit_cast(int, I), 63));
    }

    if (lane == 0) alphainv_last[r] = carry;
}

extern "C" void kernel_launch(void* const* d_in, const int* in_sizes, int n_in,
                              void* d_out, int out_size, void* d_ws, size_t ws_size,
                              hipStream_t stream) {
    const float* density  = (const float*)d_in[0];
    const float* shift    = (const float*)d_in[1];   // 1-element array
    const float* interval = (const float*)d_in[2];   // 1-element array
    const int*   ray_id   = (const int*)d_in[3];
    const int n_pts  = in_sizes[0];
    const int n_rays = out_size - n_pts;

    int*   start    = (int*)d_ws;                 // (n_rays + 1) ints of scratch
    float* weights  = (float*)d_out;              // [n_pts]
    float* alphainv = (float*)d_out + n_pts;      // [n_rays]

    {
        const int block = 256;
        const int work  = (n_pts + 3) / 4;
        const int grid  = (work + block - 1) / block;
        seg_starts_kernel<<<grid, block, 0, stream>>>(ray_id, n_pts, n_rays, start);
    }
    {
        const int waves_per_block = 4;            // block = 256 threads
        const int block = waves_per_block * 64;
        const int grid  = (n_rays + waves_per_block - 1) / waves_per_block;
        alpha_weights_kernel<<<grid, block, 0, stream>>>(
            density, shift, interval, start, weights, alphainv, n_rays);
    }
}